// Round 1
// baseline (197.927 us; speedup 1.0000x reference)
//
#include <hip/hip_runtime.h>
#include <math.h>

// Problem constants: predicted/target are (B,T,H,W,1) fp32
#define BB 8
#define TT 16
#define HH 256
#define WW 256
#define NIMG (BB * TT)          // 128 images
#define NPX  (TT * HH * WW)     // 1,048,576 px per sample
#define CROWS 64                // output rows per block (4 chunks per image)

// ws layout (float/uint indices)
#define WS_MINP 0    // 8 uint  (orderable-mapped float)
#define WS_MAXP 8    // 8 uint
#define WS_MINT 16   // 8 uint
#define WS_MAXT 24   // 8 uint
#define WS_SUMT 32   // 8 float
#define WS_PRM  40   // 8*4 float: p_scale, p_bias, t_scale, t_bias
#define WS_VALID 72  // 8 float
#define WS_SV   80   // 1 float: sum of valid
#define WS_S    81   // 1 float: sum_b valid_b * sum(ssim_map_b)

// Map float -> uint preserving order (for atomicMin/Max), and inverse.
__device__ __forceinline__ unsigned fmap(float f) {
  unsigned u = __float_as_uint(f);
  return (u & 0x80000000u) ? ~u : (u | 0x80000000u);
}
__device__ __forceinline__ float funmap(unsigned m) {
  unsigned u = (m & 0x80000000u) ? (m ^ 0x80000000u) : ~m;
  return __uint_as_float(u);
}

__global__ void k_init(unsigned* wsu, float* wsf) {
  int i = threadIdx.x;
  if (i < 8) {
    wsu[WS_MINP + i] = 0xFFFFFFFFu;
    wsu[WS_MAXP + i] = 0u;
    wsu[WS_MINT + i] = 0xFFFFFFFFu;
    wsu[WS_MAXT + i] = 0u;
    wsf[WS_SUMT + i] = 0.f;
  }
}

// Per-sample min/max of pred & targ + sum(targ). 64 blocks per sample.
__global__ __launch_bounds__(256) void k_reduce(const float* __restrict__ p,
                                                const float* __restrict__ t,
                                                unsigned* wsu, float* wsf) {
  const int b = blockIdx.x >> 6;
  const int chunk = blockIdx.x & 63;
  const size_t base = (size_t)b * NPX + (size_t)chunk * (NPX / 64);
  const int tid = threadIdx.x;

  float mnp = 3.4e38f, mxp = -3.4e38f, mnt = 3.4e38f, mxt = -3.4e38f, st = 0.f;
  const float4* p4 = (const float4*)(p + base);
  const float4* t4 = (const float4*)(t + base);
#pragma unroll 4
  for (int it = 0; it < 16; ++it) {
    float4 a = p4[it * 256 + tid];
    float4 c = t4[it * 256 + tid];
    mnp = fminf(mnp, fminf(fminf(a.x, a.y), fminf(a.z, a.w)));
    mxp = fmaxf(mxp, fmaxf(fmaxf(a.x, a.y), fmaxf(a.z, a.w)));
    mnt = fminf(mnt, fminf(fminf(c.x, c.y), fminf(c.z, c.w)));
    mxt = fmaxf(mxt, fmaxf(fmaxf(c.x, c.y), fmaxf(c.z, c.w)));
    st += c.x + c.y + c.z + c.w;
  }
  // wave64 reduce
  for (int off = 32; off > 0; off >>= 1) {
    mnp = fminf(mnp, __shfl_down(mnp, off));
    mxp = fmaxf(mxp, __shfl_down(mxp, off));
    mnt = fminf(mnt, __shfl_down(mnt, off));
    mxt = fmaxf(mxt, __shfl_down(mxt, off));
    st += __shfl_down(st, off);
  }
  __shared__ float s_mnp[4], s_mxp[4], s_mnt[4], s_mxt[4], s_st[4];
  int wave = tid >> 6, lane = tid & 63;
  if (lane == 0) {
    s_mnp[wave] = mnp; s_mxp[wave] = mxp;
    s_mnt[wave] = mnt; s_mxt[wave] = mxt; s_st[wave] = st;
  }
  __syncthreads();
  if (tid == 0) {
    for (int w = 1; w < 4; ++w) {
      mnp = fminf(mnp, s_mnp[w]); mxp = fmaxf(mxp, s_mxp[w]);
      mnt = fminf(mnt, s_mnt[w]); mxt = fmaxf(mxt, s_mxt[w]);
      st += s_st[w];
    }
    atomicMin(&wsu[WS_MINP + b], fmap(mnp));
    atomicMax(&wsu[WS_MAXP + b], fmap(mxp));
    atomicMin(&wsu[WS_MINT + b], fmap(mnt));
    atomicMax(&wsu[WS_MAXT + b], fmap(mxt));
    atomicAdd(&wsf[WS_SUMT + b], st);
  }
}

__global__ void k_params(unsigned* wsu, float* wsf) {
  if (threadIdx.x == 0 && blockIdx.x == 0) {
    float sv = 0.f;
    for (int b = 0; b < 8; ++b) {
      float mnp = funmap(wsu[WS_MINP + b]);
      float mxp = funmap(wsu[WS_MAXP + b]);
      float mnt = funmap(wsu[WS_MINT + b]);
      float mxt = funmap(wsu[WS_MAXT + b]);
      float ps = 1.f / fmaxf(mxp - mnp, 1e-6f);
      float ts = 1.f / fmaxf(mxt - mnt, 1e-6f);
      wsf[WS_PRM + b * 4 + 0] = ps;
      wsf[WS_PRM + b * 4 + 1] = -mnp * ps;
      wsf[WS_PRM + b * 4 + 2] = ts;
      wsf[WS_PRM + b * 4 + 3] = -mnt * ts;
      float v = (wsf[WS_SUMT + b] != 0.f) ? 1.f : 0.f;
      wsf[WS_VALID + b] = v;
      sv += v;
    }
    wsf[WS_SV] = sv;
    wsf[WS_S] = 0.f;
  }
}

// Fused separable-conv SSIM. One block = one image x one 64-row chunk.
// Thread = one column. Horizontal 11-tap from LDS-staged normalized rows;
// vertical 11-tap from a statically-indexed register ring (row loop unrolled
// by 11). Zero padding handled by writing 0 for OOB rows/cols.
__global__ __launch_bounds__(256) void k_ssim(const float* __restrict__ pred,
                                              const float* __restrict__ targ,
                                              float* __restrict__ wsf) {
  const int img = blockIdx.x >> 2;
  const int chunk = blockIdx.x & 3;
  const int b = img >> 4;  // img / TT
  const int x = threadIdx.x;
  const int y0 = chunk * CROWS;
  const size_t base = (size_t)img * (HH * WW);

  const float ps = wsf[WS_PRM + b * 4 + 0];
  const float pb = wsf[WS_PRM + b * 4 + 1];
  const float ts = wsf[WS_PRM + b * 4 + 2];
  const float tb = wsf[WS_PRM + b * 4 + 3];

  // Gaussian taps (match reference fp32 computation)
  float g[11];
  {
    float s = 0.f;
#pragma unroll
    for (int i = 0; i < 11; ++i) {
      float d = (float)(i - 5);
      g[i] = expf(-d * d / 4.5f);
      s += g[i];
    }
    float inv = 1.f / s;
#pragma unroll
    for (int i = 0; i < 11; ++i) g[i] *= inv;
  }

  // Double-buffered staging rows with 5-wide zero halos: col x -> index x+5
  __shared__ float rowt[2][WW + 12];
  __shared__ float rowp[2][WW + 12];
  if (x < 5) {
    rowt[0][x] = 0.f; rowt[1][x] = 0.f;
    rowp[0][x] = 0.f; rowp[1][x] = 0.f;
    rowt[0][WW + 5 + x] = 0.f; rowt[1][WW + 5 + x] = 0.f;
    rowp[0][WW + 5 + x] = 0.f; rowp[1][WW + 5 + x] = 0.f;
  }
  __syncthreads();

  // Register ring: horizontal conv results for 11 consecutive rows
  float r_mu1[11], r_mu2[11], r_t2[11], r_p2[11], r_tp[11];
  float acc = 0.f;
  const int ystart = y0 - 10;
  int buf = 0;

  const float C1 = 1e-4f, C2 = 9e-4f, C3 = 4.5e-4f;

#pragma unroll 1
  for (int yb = 0; yb < 88; yb += 11) {
#pragma unroll
    for (int j = 0; j < 11; ++j) {
      const int y = ystart + yb + j;
      float tn = 0.f, pn = 0.f;
      if (y >= 0 && y < HH) {  // wave-uniform
        float tv = targ[base + (size_t)y * WW + x];
        float pv = pred[base + (size_t)y * WW + x];
        tn = tv * ts + tb;
        pn = pv * ps + pb;
      }
      rowt[buf][x + 5] = tn;
      rowp[buf][x + 5] = pn;
      __syncthreads();

      float mu1 = 0.f, mu2 = 0.f, t2 = 0.f, p2 = 0.f, tp = 0.f;
#pragma unroll
      for (int k = 0; k < 11; ++k) {
        float tk = rowt[buf][x + k];
        float pk = rowp[buf][x + k];
        float gt = g[k] * tk;
        float gp = g[k] * pk;
        mu1 += gt;
        mu2 += gp;
        t2 += gt * tk;
        p2 += gp * pk;
        tp += gt * pk;
      }
      r_mu1[j] = mu1; r_mu2[j] = mu2;
      r_t2[j] = t2;   r_p2[j] = p2;  r_tp[j] = tp;
      buf ^= 1;

      const int yo = y - 5;
      if (yo >= y0 && yo < y0 + CROWS) {  // wave-uniform
        float v1 = 0.f, v2 = 0.f, vt2 = 0.f, vp2 = 0.f, vtp = 0.f;
#pragma unroll
        for (int k = 0; k < 11; ++k) {
          const int slot = (j + k + 1) % 11;  // compile-time constant
          v1 += g[k] * r_mu1[slot];
          v2 += g[k] * r_mu2[slot];
          vt2 += g[k] * r_t2[slot];
          vp2 += g[k] * r_p2[slot];
          vtp += g[k] * r_tp[slot];
        }
        float mu1s = v1 * v1, mu2s = v2 * v2, m12 = v1 * v2;
        float s1 = fmaxf(vt2 - mu1s, 1e-6f);
        float s2 = fmaxf(vp2 - mu2s, 1e-6f);
        float s12 = vtp - m12;
        float root = sqrtf(s1 * s2);
        float lum = (2.f * m12 + C1) / (mu1s + mu2s + C1);
        float con = (2.f * root + C2) / (s1 + s2 + C2);
        float str = (s12 + C3) / (root + C3);
        acc += lum * con * str;
      }
    }
  }

  // Block reduction + valid-weighted atomic accumulate
  __shared__ float red[256];
  red[x] = acc;
  __syncthreads();
#pragma unroll
  for (int s = 128; s > 0; s >>= 1) {
    if (x < s) red[x] += red[x + s];
    __syncthreads();
  }
  if (x == 0) atomicAdd(&wsf[WS_S], red[0] * wsf[WS_VALID + b]);
}

__global__ void k_loss(const float* __restrict__ wsf, float* __restrict__ out) {
  if (threadIdx.x == 0 && blockIdx.x == 0) {
    float sv = wsf[WS_SV];
    float S = wsf[WS_S];
    out[0] = (sv - S * (1.f / (float)NPX)) / fmaxf(sv, 1.f);
  }
}

extern "C" void kernel_launch(void* const* d_in, const int* in_sizes, int n_in,
                              void* d_out, int out_size, void* d_ws, size_t ws_size,
                              hipStream_t stream) {
  const float* pred = (const float*)d_in[0];
  const float* targ = (const float*)d_in[1];
  float* wsf = (float*)d_ws;
  unsigned* wsu = (unsigned*)d_ws;
  float* out = (float*)d_out;

  hipLaunchKernelGGL(k_init, dim3(1), dim3(64), 0, stream, wsu, wsf);
  hipLaunchKernelGGL(k_reduce, dim3(512), dim3(256), 0, stream, pred, targ, wsu, wsf);
  hipLaunchKernelGGL(k_params, dim3(1), dim3(64), 0, stream, wsu, wsf);
  hipLaunchKernelGGL(k_ssim, dim3(512), dim3(256), 0, stream, pred, targ, wsf);
  hipLaunchKernelGGL(k_loss, dim3(1), dim3(64), 0, stream, wsf, out);
}

// Round 2
// 168.175 us; speedup vs baseline: 1.1769x; 1.1769x over previous
//
#include <hip/hip_runtime.h>
#include <math.h>
#include <utility>

// predicted/target: (B,T,H,W,1) fp32
#define BB 8
#define TT 16
#define HH 256
#define WW 256
#define NPX (TT * HH * WW)      // 1,048,576 px per sample
#define CROWS 32                // output rows per ssim block
#define NCHUNK (HH / CROWS)     // 8
#define NBLK (BB * TT * NCHUNK) // 1024 ssim blocks

// ws float layout (per-block partials from k_reduce; 512 = 8 samples x 64 chunks)
#define P_MINP 0
#define P_MAXP 512
#define P_MINT 1024
#define P_MAXT 1536
#define P_SUMT 2048
#define WS_S   2560   // accumulated valid-weighted ssim sum

template <int... J, typename F>
__device__ __forceinline__ void sf_impl(std::integer_sequence<int, J...>, F&& f) {
  (f(std::integral_constant<int, J>{}), ...);
}
template <int N, typename F>
__device__ __forceinline__ void static_for(F&& f) {
  sf_impl(std::make_integer_sequence<int, N>{}, (F&&)f);
}

// Per-sample min/max of pred & targ + sum(targ), one partial per block.
__global__ __launch_bounds__(256) void k_reduce(const float* __restrict__ p,
                                                const float* __restrict__ t,
                                                float* __restrict__ wsf) {
  const int b = blockIdx.x >> 6;
  const size_t base = (size_t)b * NPX + (size_t)(blockIdx.x & 63) * (NPX / 64);
  const int tid = threadIdx.x;

  float mnp = 3.4e38f, mxp = -3.4e38f, mnt = 3.4e38f, mxt = -3.4e38f, st = 0.f;
  const float4* p4 = (const float4*)(p + base);
  const float4* t4 = (const float4*)(t + base);
#pragma unroll 4
  for (int it = 0; it < 16; ++it) {
    float4 a = p4[it * 256 + tid];
    float4 c = t4[it * 256 + tid];
    mnp = fminf(mnp, fminf(fminf(a.x, a.y), fminf(a.z, a.w)));
    mxp = fmaxf(mxp, fmaxf(fmaxf(a.x, a.y), fmaxf(a.z, a.w)));
    mnt = fminf(mnt, fminf(fminf(c.x, c.y), fminf(c.z, c.w)));
    mxt = fmaxf(mxt, fmaxf(fmaxf(c.x, c.y), fmaxf(c.z, c.w)));
    st += c.x + c.y + c.z + c.w;
  }
  for (int off = 32; off > 0; off >>= 1) {
    mnp = fminf(mnp, __shfl_down(mnp, off));
    mxp = fmaxf(mxp, __shfl_down(mxp, off));
    mnt = fminf(mnt, __shfl_down(mnt, off));
    mxt = fmaxf(mxt, __shfl_down(mxt, off));
    st += __shfl_down(st, off);
  }
  __shared__ float s_mnp[4], s_mxp[4], s_mnt[4], s_mxt[4], s_st[4];
  int wave = tid >> 6, lane = tid & 63;
  if (lane == 0) {
    s_mnp[wave] = mnp; s_mxp[wave] = mxp;
    s_mnt[wave] = mnt; s_mxt[wave] = mxt; s_st[wave] = st;
  }
  __syncthreads();
  if (tid == 0) {
    for (int w = 1; w < 4; ++w) {
      mnp = fminf(mnp, s_mnp[w]); mxp = fmaxf(mxp, s_mxp[w]);
      mnt = fminf(mnt, s_mnt[w]); mxt = fmaxf(mxt, s_mxt[w]);
      st += s_st[w];
    }
    wsf[P_MINP + blockIdx.x] = mnp;
    wsf[P_MAXP + blockIdx.x] = mxp;
    wsf[P_MINT + blockIdx.x] = mnt;
    wsf[P_MAXT + blockIdx.x] = mxt;
    wsf[P_SUMT + blockIdx.x] = st;
    if (blockIdx.x == 0) wsf[WS_S] = 0.f;
  }
}

// Fused separable-conv SSIM. Block = one image x one 32-row chunk.
// Thread = one column. H-conv from LDS-staged normalized rows; V-conv from a
// STATICALLY-indexed 55-register ring (phase j and tap k are constexpr via
// static_for, so the ring cannot be demoted to scratch).
__global__ __launch_bounds__(256, 4) void k_ssim(const float* __restrict__ pred,
                                                 const float* __restrict__ targ,
                                                 float* __restrict__ wsf) {
  const int img = blockIdx.x >> 3;    // 0..127
  const int chunk = blockIdx.x & 7;   // 0..7
  const int b = img >> 4;             // sample
  const int x = threadIdx.x;
  const int y0 = chunk * CROWS;
  const size_t base = (size_t)img * (HH * WW);

  // Preamble: reduce this sample's 64 partials -> norm params + valid (wave 0)
  __shared__ float sprm[5];  // ps, pb, ts, tb, valid
  if (x < 64) {
    float mnp = wsf[P_MINP + b * 64 + x];
    float mxp = wsf[P_MAXP + b * 64 + x];
    float mnt = wsf[P_MINT + b * 64 + x];
    float mxt = wsf[P_MAXT + b * 64 + x];
    float st  = wsf[P_SUMT + b * 64 + x];
    for (int off = 32; off > 0; off >>= 1) {
      mnp = fminf(mnp, __shfl_down(mnp, off));
      mxp = fmaxf(mxp, __shfl_down(mxp, off));
      mnt = fminf(mnt, __shfl_down(mnt, off));
      mxt = fmaxf(mxt, __shfl_down(mxt, off));
      st += __shfl_down(st, off);
    }
    if (x == 0) {
      float ps = 1.f / fmaxf(mxp - mnp, 1e-6f);
      float tsc = 1.f / fmaxf(mxt - mnt, 1e-6f);
      sprm[0] = ps; sprm[1] = -mnp * ps;
      sprm[2] = tsc; sprm[3] = -mnt * tsc;
      sprm[4] = (st != 0.f) ? 1.f : 0.f;
    }
  }

  // Gaussian taps
  float g[11];
  {
    float s = 0.f;
#pragma unroll
    for (int i = 0; i < 11; ++i) {
      float d = (float)(i - 5);
      g[i] = expf(-d * d / 4.5f);
      s += g[i];
    }
    float inv = 1.f / s;
#pragma unroll
    for (int i = 0; i < 11; ++i) g[i] *= inv;
  }

  // Double-buffered staging rows, 5-wide zero halos: col x -> index x+5
  __shared__ float rowt[2][WW + 12];
  __shared__ float rowp[2][WW + 12];
  if (x < 5) {
    rowt[0][x] = 0.f; rowt[1][x] = 0.f;
    rowp[0][x] = 0.f; rowp[1][x] = 0.f;
    rowt[0][WW + 5 + x] = 0.f; rowt[1][WW + 5 + x] = 0.f;
    rowp[0][WW + 5 + x] = 0.f; rowp[1][WW + 5 + x] = 0.f;
  }
  __syncthreads();
  const float ps = sprm[0], pb = sprm[1], ts = sprm[2], tb = sprm[3];

  // Register ring: H-conv results for 11 consecutive rows, 5 channels
  float r_mu1[11], r_mu2[11], r_t2[11], r_p2[11], r_tp[11];
  float acc = 0.f;
  int buf = 0;
  const int ystart = y0 - 5;  // iteration i stages row ystart+i; output yo=row-5
  const float C1 = 1e-4f, C2 = 9e-4f, C3 = 4.5e-4f;

#pragma unroll 1
  for (int grp = 0; grp < 4; ++grp) {
    static_for<11>([&](auto jc) {
      constexpr int j = decltype(jc)::value;
      const int i = grp * 11 + j;
      if (i < 42) {  // block-uniform; rows beyond i=41 feed nothing
        const int y = ystart + i;
        float tn = 0.f, pn = 0.f;
        if ((unsigned)y < (unsigned)HH) {  // block-uniform
          tn = fmaf(targ[base + (size_t)y * WW + x], ts, tb);
          pn = fmaf(pred[base + (size_t)y * WW + x], ps, pb);
        }
        rowt[buf][x + 5] = tn;
        rowp[buf][x + 5] = pn;
        __syncthreads();

        float mu1 = 0.f, mu2 = 0.f, t2 = 0.f, p2 = 0.f, tp = 0.f;
#pragma unroll
        for (int k = 0; k < 11; ++k) {
          float tk = rowt[buf][x + k];
          float pk = rowp[buf][x + k];
          float gt = g[k] * tk;
          float gp = g[k] * pk;
          mu1 += gt; mu2 += gp;
          t2 += gt * tk; p2 += gp * pk; tp += gt * pk;
        }
        r_mu1[j] = mu1; r_mu2[j] = mu2;
        r_t2[j] = t2;   r_p2[j] = p2;  r_tp[j] = tp;
        buf ^= 1;

        if (i >= 10) {  // block-uniform: outputs i=10..41 -> yo=y0..y0+31
          float v1 = 0.f, v2 = 0.f, vt2 = 0.f, vp2 = 0.f, vtp = 0.f;
          static_for<11>([&](auto kc) {
            constexpr int k = decltype(kc)::value;
            constexpr int slot = (j + 1 + k) % 11;  // truly constexpr
            v1  += g[k] * r_mu1[slot];
            v2  += g[k] * r_mu2[slot];
            vt2 += g[k] * r_t2[slot];
            vp2 += g[k] * r_p2[slot];
            vtp += g[k] * r_tp[slot];
          });
          float mu1s = v1 * v1, mu2s = v2 * v2, m12 = v1 * v2;
          float s1 = fmaxf(vt2 - mu1s, 1e-6f);
          float s2 = fmaxf(vp2 - mu2s, 1e-6f);
          float s12 = vtp - m12;
          float root = sqrtf(s1 * s2);
          float lum = (2.f * m12 + C1) / (mu1s + mu2s + C1);
          float con = (2.f * root + C2) / (s1 + s2 + C2);
          float str = (s12 + C3) / (root + C3);
          acc += lum * con * str;
        }
      }
    });
  }

  // Block reduction + valid-weighted accumulate
  for (int off = 32; off > 0; off >>= 1) acc += __shfl_down(acc, off);
  __shared__ float sred[4];
  if ((x & 63) == 0) sred[x >> 6] = acc;
  __syncthreads();
  if (x == 0) {
    float v = sred[0] + sred[1] + sred[2] + sred[3];
    atomicAdd(&wsf[WS_S], v * sprm[4]);
  }
}

__global__ void k_loss(const float* __restrict__ wsf, float* __restrict__ out) {
  const int c = threadIdx.x;  // 64 threads
  float sums[8];
#pragma unroll
  for (int b = 0; b < 8; ++b) sums[b] = wsf[P_SUMT + b * 64 + c];
  for (int off = 32; off > 0; off >>= 1) {
#pragma unroll
    for (int b = 0; b < 8; ++b) sums[b] += __shfl_down(sums[b], off);
  }
  if (c == 0) {
    float sv = 0.f;
#pragma unroll
    for (int b = 0; b < 8; ++b) sv += (sums[b] != 0.f) ? 1.f : 0.f;
    float S = wsf[WS_S];
    out[0] = (sv - S * (1.f / (float)NPX)) / fmaxf(sv, 1.f);
  }
}

extern "C" void kernel_launch(void* const* d_in, const int* in_sizes, int n_in,
                              void* d_out, int out_size, void* d_ws, size_t ws_size,
                              hipStream_t stream) {
  const float* pred = (const float*)d_in[0];
  const float* targ = (const float*)d_in[1];
  float* wsf = (float*)d_ws;
  float* out = (float*)d_out;

  hipLaunchKernelGGL(k_reduce, dim3(512), dim3(256), 0, stream, pred, targ, wsf);
  hipLaunchKernelGGL(k_ssim, dim3(NBLK), dim3(256), 0, stream, pred, targ, wsf);
  hipLaunchKernelGGL(k_loss, dim3(1), dim3(64), 0, stream, wsf, out);
}